// Round 17
// baseline (232.731 us; speedup 1.0000x reference)
//
#include <hip/hip_runtime.h>
#include <hip/hip_bf16.h>
#include <math.h>

#define NN 512
#define DD 128
#define NP (NN*NN)   // 262144

// d-major slabs: skewed pitch 512KB + 4KB + 256B. The 4KB component spreads
// consecutive d-slabs across DIFFERENT channel-interleave granules (R16's
// 256B-only skew left a block's 64 d-runs in ~4 granules -> ~2.2 TB/s writes).
#define PITCH ((size_t)(NP * 2 + 4096 + 256))

typedef __attribute__((ext_vector_type(4))) float f32x4;
typedef __attribute__((ext_vector_type(8))) short bf16x8;
typedef __attribute__((ext_vector_type(4))) unsigned int u32x4;

__device__ __forceinline__ unsigned short f2bf(float f) {
  union { float f; unsigned u; } v; v.f = f;
  unsigned r = v.u + 0x7FFFu + ((v.u >> 16) & 1u);
  return (unsigned short)(r >> 16);
}
__device__ __forceinline__ float bf2f(unsigned short h) {
  union { unsigned u; float f; } v; v.u = ((unsigned)h) << 16;
  return v.f;
}
__device__ __forceinline__ float sigmoidf_(float x) {
  return __builtin_amdgcn_rcpf(1.0f + __expf(-x));
}
__device__ __forceinline__ unsigned pkbf2(float a, float b) {
  float2 t; t.x = a; t.y = b;
  __hip_bfloat162 h = __float22bfloat162_rn(t);
  unsigned r; __builtin_memcpy(&r, &h, 4); return r;
}
__device__ __forceinline__ void ntstore16(void* p, uint4 v) {
  u32x4 w; __builtin_memcpy(&w, &v, 16);
  __builtin_nontemporal_store(w, (u32x4*)p);
}

__device__ __forceinline__ void gll16(void* lds, const void* g) {
  __builtin_amdgcn_global_load_lds(
      (const __attribute__((address_space(1))) void*)g,
      (__attribute__((address_space(3))) void*)lds, 16, 0, 0);
}

// wprep byte-layout: P[256 cols] @0, G[256 cols] @65536, GO[128] @131072, PO[128] @163840
#define WP_P  0
#define WP_G  65536
#define WP_GO 131072
#define WP_PO 163840

__global__ __launch_bounds__(256) void kw_prep(const float* __restrict__ w_p_in,
    const float* __restrict__ w_g_in, const float* __restrict__ w_g_out,
    const float* __restrict__ w_p_out, unsigned short* __restrict__ wprep) {
  int idx = blockIdx.x * 256 + threadIdx.x;   // 0..98303
  int n, k, base; float v;
  if (idx < 32768)       { n = idx >> 7;          k = idx & 127; v = w_p_in[k * 256 + n];  base = WP_P; }
  else if (idx < 65536)  { int e = idx - 32768;  n = e >> 7; k = e & 127; v = w_g_in[k * 256 + n];  base = WP_G; }
  else if (idx < 81920)  { int e = idx - 65536;  n = e >> 7; k = e & 127; v = w_g_out[k * 128 + n]; base = WP_GO; }
  else                   { int e = idx - 81920;  n = e >> 7; k = e & 127; v = w_p_out[k * 128 + n]; base = WP_PO; }
  int dst = base + n * 256 + ((2 * k) ^ ((n & 7) << 4));
  wprep[dst >> 1] = f2bf(v);
}

// ---------------- KA: layernorm(x) -> xn_sw (PRE-SWIZZLED global bf16 image) --
__global__ __launch_bounds__(256) void kA_ln(const float* __restrict__ x,
    const float* __restrict__ nw, const float* __restrict__ nb,
    unsigned short* __restrict__ xn_sw) {
  const int tid = threadIdx.x;
  const int l16 = tid & 15, rsub = tid >> 4;
  const int row0 = blockIdx.x * 64;
  const float4 wv0 = *(const float4*)(nw + l16 * 8);
  const float4 wv1 = *(const float4*)(nw + l16 * 8 + 4);
  const float4 bv0 = *(const float4*)(nb + l16 * 8);
  const float4 bv1 = *(const float4*)(nb + l16 * 8 + 4);
  #pragma unroll
  for (int rnd = 0; rnd < 4; ++rnd) {
    int r = row0 + rnd * 16 + rsub;
    const f32x4* xr = (const f32x4*)(x + (size_t)r * DD + l16 * 8);
    f32x4 a0 = __builtin_nontemporal_load(xr);
    f32x4 a1 = __builtin_nontemporal_load(xr + 1);
    float4 v0 = *(float4*)&a0, v1 = *(float4*)&a1;
    float s = v0.x + v0.y + v0.z + v0.w + v1.x + v1.y + v1.z + v1.w;
    float q = v0.x*v0.x + v0.y*v0.y + v0.z*v0.z + v0.w*v0.w
            + v1.x*v1.x + v1.y*v1.y + v1.z*v1.z + v1.w*v1.w;
    #pragma unroll
    for (int m = 8; m; m >>= 1) { s += __shfl_xor(s, m); q += __shfl_xor(q, m); }
    float mean = s * (1.0f / DD);
    float var = q * (1.0f / DD) - mean * mean;
    float rstd = rsqrtf(var + 1e-5f);
    uint4 pk;
    pk.x = pkbf2((v0.x - mean) * rstd * wv0.x + bv0.x, (v0.y - mean) * rstd * wv0.y + bv0.y);
    pk.y = pkbf2((v0.z - mean) * rstd * wv0.z + bv0.z, (v0.w - mean) * rstd * wv0.w + bv0.w);
    pk.z = pkbf2((v1.x - mean) * rstd * wv1.x + bv1.x, (v1.y - mean) * rstd * wv1.y + bv1.y);
    pk.w = pkbf2((v1.z - mean) * rstd * wv1.z + bv1.z, (v1.w - mean) * rstd * wv1.w + bv1.w);
    *(uint4*)((unsigned char*)xn_sw + (size_t)r * 256 + ((l16 * 16) ^ ((r & 7) << 4))) = pk;
  }
}

// ---------------- KB: ONE gated GEMM pass per block (grid 8192, 1D) -----------
// Remap: q=(bid>>3)&3, rt=(bid&7)|((bid>>5)<<3) -> xn L2-hot (same XCD,
// temporally adjacent). Weights prefetched to registers before the barrier.
// Epilogue stages into sxn -> 256B-dense nt stores, 4KB-granule d-spread.
__global__ __launch_bounds__(256) void kB_gemm(
    const unsigned short* __restrict__ xn_sw, const float* __restrict__ mask,
    const unsigned short* __restrict__ wprep,
    unsigned char* __restrict__ a_t, unsigned char* __restrict__ b_t) {
  const int bid = blockIdx.x;
  const int q = (bid >> 3) & 3;                       // 0..3
  const int rt = (bid & 7) | ((bid >> 5) << 3);       // row-tile 0..2047
  const int row0 = rt * 128;
  const int i_idx = row0 >> 9;           // i coordinate
  const int kb = (row0 & 511) >> 7;      // k-granule 0..3
  const int tid = threadIdx.x, lane = tid & 63, wv = tid >> 6;
  const int wr = wv >> 1, wc = wv & 1;
  __shared__ __align__(16) unsigned char sxn[32768];   // staging image, then epilogue
  __shared__ float smask[128];

  const unsigned char* wp = (const unsigned char*)wprep;

  // prefetch weights into registers (independent of staging)
  bf16x8 wP[4][2], wG[4][2];
  #pragma unroll
  for (int ks = 0; ks < 4; ++ks) {
    int kbb = ks * 64 + (lane >> 4) * 16;
    #pragma unroll
    for (int ni = 0; ni < 2; ++ni) {
      int n = q * 64 + wc * 32 + ni * 16 + (lane & 15);
      int off = n * 256 + (kbb ^ ((n & 7) << 4));
      wP[ks][ni] = *(const bf16x8*)(wp + WP_P + off);
      wG[ks][ni] = *(const bf16x8*)(wp + WP_G + off);
    }
  }

  #pragma unroll
  for (int it = 0; it < 8; ++it) {
    int o = it * 4096 + tid * 16;
    gll16(sxn + o, (const unsigned char*)xn_sw + (size_t)row0 * 256 + o);
  }
  if (tid < 128) smask[tid] = mask[row0 + tid];
  __syncthreads();

  f32x4 acc[4][4] = {};   // ni 0,1 = p ; ni 2,3 = g (same cols)
  #pragma unroll
  for (int ks = 0; ks < 4; ++ks) {
    int kbb = ks * 64 + (lane >> 4) * 16;
    bf16x8 af[4];
    #pragma unroll
    for (int mi = 0; mi < 4; ++mi) {
      int r = wr * 64 + mi * 16 + (lane & 15);
      af[mi] = *(const bf16x8*)(sxn + r * 256 + (kbb ^ ((r & 7) << 4)));
    }
    #pragma unroll
    for (int mi = 0; mi < 4; ++mi)
      #pragma unroll
      for (int ni = 0; ni < 2; ++ni) {
        acc[mi][ni]     = __builtin_amdgcn_mfma_f32_16x16x32_bf16(af[mi], wP[ks][ni], acc[mi][ni], 0, 0, 0);
        acc[mi][ni + 2] = __builtin_amdgcn_mfma_f32_16x16x32_bf16(af[mi], wG[ks][ni], acc[mi][ni + 2], 0, 0, 0);
      }
  }

  __syncthreads();   // all sxn reads done; buffer reusable for epilogue
  #pragma unroll
  for (int mi = 0; mi < 4; ++mi) {
    int rq = wr * 64 + mi * 16 + (lane >> 4) * 4;
    float mk0 = smask[rq], mk1 = smask[rq + 1], mk2 = smask[rq + 2], mk3 = smask[rq + 3];
    #pragma unroll
    for (int ni = 0; ni < 2; ++ni) {
      int drel = wc * 32 + ni * 16 + (lane & 15);
      uint2 pk;
      pk.x = pkbf2(acc[mi][ni][0] * sigmoidf_(acc[mi][ni + 2][0]) * mk0,
                   acc[mi][ni][1] * sigmoidf_(acc[mi][ni + 2][1]) * mk1);
      pk.y = pkbf2(acc[mi][ni][2] * sigmoidf_(acc[mi][ni + 2][2]) * mk2,
                   acc[mi][ni][3] * sigmoidf_(acc[mi][ni + 2][3]) * mk3);
      *(uint2*)(sxn + drel * 256 + ((rq * 2) ^ ((drel & 7) << 4))) = pk;
    }
  }
  __syncthreads();
  unsigned char* dst = (q < 2) ? a_t : b_t;
  const int dmin = (q & 1) * 64;
  #pragma unroll
  for (int it = 0; it < 4; ++it) {
    int idx = it * 256 + tid;
    int dr = idx >> 4, ch = idx & 15;
    uint4 v = *(const uint4*)(sxn + dr * 256 + ((ch * 16) ^ ((dr & 7) << 4)));
    ntstore16(dst + (size_t)(dmin + dr) * PITCH + (size_t)kb * 131072
                  + (size_t)i_idx * 256 + ch * 16, v);
  }
}

// ---------------- K2: per-d GEMM, 512 threads (8 waves, 32x64 per wave) -------
// BK=64 (8 iters), double-buffered 64KB LDS, chunk-XOR c^(i&7).
// 512 threads -> 2 blocks/CU = 16 waves/CU (2x R16's 8) for latency overlap.
// t output layout: byte(d,i,j) = ((i*512+j)>>6)*16384 + d*128 + (j&63)*2.
__global__ __launch_bounds__(512) void k2_einsum(
    const unsigned char* __restrict__ a_t, const unsigned char* __restrict__ b_t,
    unsigned char* __restrict__ t_out) {
  int bid = blockIdx.x;
  int wg = (bid & 7) * 256 + (bid >> 3);   // XCD swizzle (2048 % 8 == 0, bijective)
  int d = wg >> 4;
  int tile = wg & 15;
  int i0 = (tile >> 2) * 128, j0 = (tile & 3) * 128;
  const int tid = threadIdx.x, lane = tid & 63, wv = tid >> 6;  // wave 0..7
  const int wr = wv >> 1, wc = wv & 1;    // wr 0..3 (32-row strips), wc 0..1 (64-col)
  __shared__ __align__(16) unsigned char smem[65536];
  unsigned char* sA = smem;            // [2][16384]
  unsigned char* sB = smem + 32768;    // [2][16384]
  const unsigned char* Abase = a_t + (size_t)d * PITCH;
  const unsigned char* Bbase = b_t + (size_t)d * PITCH;

  int sil[2], sga[2];
  #pragma unroll
  for (int j = 0; j < 2; ++j) {
    int o = j * 8192 + tid * 16;
    int il = o >> 7, c = (o >> 4) & 7;
    sil[j] = o;
    sga[j] = il * 256 + ((c ^ (il & 7)) << 4);
  }

  f32x4 acc[2][4] = {};
  #pragma unroll
  for (int j = 0; j < 2; ++j) {
    gll16(sA + sil[j], Abase + (size_t)i0 * 256 + sga[j]);
    gll16(sB + sil[j], Bbase + (size_t)j0 * 256 + sga[j]);
  }
  __syncthreads();

  int cur = 0;
  for (int t = 0; t < 8; ++t) {
    if (t < 7) {
      int tn = t + 1;
      size_t koff = (size_t)(tn >> 1) * 131072 + (size_t)(tn & 1) * 128;
      int nb_ = (cur ^ 1) * 16384;
      #pragma unroll
      for (int j = 0; j < 2; ++j) {
        gll16(sA + nb_ + sil[j], Abase + koff + (size_t)i0 * 256 + sga[j]);
        gll16(sB + nb_ + sil[j], Bbase + koff + (size_t)j0 * 256 + sga[j]);
      }
    }
    int cb = cur * 16384;
    #pragma unroll
    for (int ks2 = 0; ks2 < 2; ++ks2) {
      bf16x8 af[2], bfr[4];
      int cfrag = ks2 * 4 + (lane >> 4);
      #pragma unroll
      for (int mi = 0; mi < 2; ++mi) {
        int r = wr * 32 + mi * 16 + (lane & 15);
        af[mi] = *(const bf16x8*)(sA + cb + r * 128 + ((cfrag ^ (r & 7)) << 4));
      }
      #pragma unroll
      for (int ni = 0; ni < 4; ++ni) {
        int r = wc * 64 + ni * 16 + (lane & 15);
        bfr[ni] = *(const bf16x8*)(sB + cb + r * 128 + ((cfrag ^ (r & 7)) << 4));
      }
      #pragma unroll
      for (int mi = 0; mi < 2; ++mi)
        #pragma unroll
        for (int ni = 0; ni < 4; ++ni)
          acc[mi][ni] = __builtin_amdgcn_mfma_f32_16x16x32_bf16(af[mi], bfr[ni], acc[mi][ni], 0, 0, 0);
    }
    __syncthreads();
    cur ^= 1;
  }

  // epilogue: stage [128 i][256B j] bf16 (XOR-swizzled) in smem, dense nt stores
  #pragma unroll
  for (int mi = 0; mi < 2; ++mi)
    #pragma unroll
    for (int j = 0; j < 4; ++j) {
      int il = wr * 32 + mi * 16 + (lane >> 4) * 4 + j;
      #pragma unroll
      for (int ni = 0; ni < 4; ++ni) {
        int jl = wc * 64 + ni * 16 + (lane & 15);
        *(unsigned short*)(smem + il * 256 + ((jl * 2) ^ ((il & 7) << 4))) = f2bf(acc[mi][ni][j]);
      }
    }
  __syncthreads();
  #pragma unroll
  for (int rr = 0; rr < 4; ++rr) {
    int u = rr * 512 + tid;
    int il = u >> 4, sub = u & 15;
    int jg = sub >> 3, cc = sub & 7;
    uint4 v = *(const uint4*)(smem + il * 256 + ((sub * 16) ^ ((il & 7) << 4)));
    ntstore16(t_out + ((size_t)(i0 + il) * 8 + (j0 >> 6) + jg) * 16384
                    + (size_t)d * 128 + cc * 16, v);
  }
}

// ---------------- K3: LN over d + (tn @ w_p_out) * sigmoid(xn @ w_g_out) ------
// t-read is ONE contiguous 16KB block (t2[pb][d][64] layout == sT layout).
__global__ __launch_bounds__(256) void k3_out(
    const unsigned char* __restrict__ t_in, const unsigned short* __restrict__ xn_sw,
    const unsigned short* __restrict__ wprep,
    const float* __restrict__ now, const float* __restrict__ nob,
    float* __restrict__ out) {
  const int p0 = blockIdx.x * 64;
  const int tid = threadIdx.x, lane = tid & 63, wv = tid >> 6;
  const int wr = wv >> 1, wc = wv & 1;
  __shared__ __align__(16) unsigned char sm[49152];
  unsigned short* sT = (unsigned short*)sm;        // [d][p] bf16, 16KB
  unsigned char* sTN = sm + 16384;                 // [p][d] swizzled, 16KB
  unsigned char* sxn = sm + 32768;                 // xn rows swizzled, 16KB
  __shared__ float ps[4][64], pq[4][64], smean[64], srstd[64];

  #pragma unroll
  for (int it = 0; it < 4; ++it) {
    int o = it * 4096 + tid * 16;
    gll16((unsigned char*)sT + o, t_in + (size_t)blockIdx.x * 16384 + o);
  }
  #pragma unroll
  for (int it = 0; it < 4; ++it) {
    int o = it * 4096 + tid * 16;
    gll16(sxn + o, (const unsigned char*)xn_sw + (size_t)p0 * 256 + o);
  }
  __syncthreads();
  const int p = tid & 63, dh = tid >> 6;
  {
    float s = 0.f, q = 0.f;
    #pragma unroll
    for (int dd = 0; dd < 32; ++dd) {
      float v = bf2f(sT[(dh * 32 + dd) * 64 + p]);
      s += v; q += v * v;
    }
    ps[dh][p] = s; pq[dh][p] = q;
  }
  __syncthreads();
  if (tid < 64) {
    float s = ps[0][tid] + ps[1][tid] + ps[2][tid] + ps[3][tid];
    float q = pq[0][tid] + pq[1][tid] + pq[2][tid] + pq[3][tid];
    float mean = s * (1.0f / 128.0f);
    float var = q * (1.0f / 128.0f) - mean * mean;
    smean[tid] = mean; srstd[tid] = rsqrtf(var + 1e-5f);
  }
  __syncthreads();
  {
    float mean = smean[p], rstd = srstd[p];
    #pragma unroll
    for (int e = 0; e < 16; ++e) {
      int d0 = dh * 32 + e * 2;
      float v0 = (bf2f(sT[d0 * 64 + p]) - mean) * rstd * now[d0] + nob[d0];
      float v1 = (bf2f(sT[(d0 + 1) * 64 + p]) - mean) * rstd * now[d0 + 1] + nob[d0 + 1];
      unsigned pack = pkbf2(v0, v1);
      *(unsigned*)(sTN + p * 256 + ((d0 * 2) ^ ((p & 7) << 4))) = pack;
    }
  }
  __syncthreads();
  f32x4 accP[2][4] = {}, accG[2][4] = {};
  const unsigned char* wpo = (const unsigned char*)wprep + WP_PO;
  const unsigned char* wgo = (const unsigned char*)wprep + WP_GO;
  #pragma unroll
  for (int ks = 0; ks < 4; ++ks) {
    int kbb = ks * 64 + (lane >> 4) * 16;
    bf16x8 af[2], ag[2], bP[4], bG[4];
    #pragma unroll
    for (int mi = 0; mi < 2; ++mi) {
      int r = wr * 32 + mi * 16 + (lane & 15);
      int off = r * 256 + (kbb ^ ((r & 7) << 4));
      af[mi] = *(const bf16x8*)(sTN + off);
      ag[mi] = *(const bf16x8*)(sxn + off);
    }
    #pragma unroll
    for (int ni = 0; ni < 4; ++ni) {
      int n = wc * 64 + ni * 16 + (lane & 15);
      int off = n * 256 + (kbb ^ ((n & 7) << 4));
      bP[ni] = *(const bf16x8*)(wpo + off);
      bG[ni] = *(const bf16x8*)(wgo + off);
    }
    #pragma unroll
    for (int mi = 0; mi < 2; ++mi)
      #pragma unroll
      for (int ni = 0; ni < 4; ++ni) {
        accP[mi][ni] = __builtin_amdgcn_mfma_f32_16x16x32_bf16(af[mi], bP[ni], accP[mi][ni], 0, 0, 0);
        accG[mi][ni] = __builtin_amdgcn_mfma_f32_16x16x32_bf16(ag[mi], bG[ni], accG[mi][ni], 0, 0, 0);
      }
  }
  // epilogue: stage f32 [64 p][512B], 64B-window XOR by (p>>2)&3 -> dense nt stores
  __syncthreads();
  #pragma unroll
  for (int mi = 0; mi < 2; ++mi)
    #pragma unroll
    for (int ni = 0; ni < 4; ++ni) {
      int nb4 = (wc * 256 + ni * 64 + (lane & 15) * 4);
      int prow = wr * 32 + mi * 16 + (lane >> 4) * 4;
      #pragma unroll
      for (int j = 0; j < 4; ++j) {
        int pp = prow + j;
        float v = accP[mi][ni][j] * sigmoidf_(accG[mi][ni][j]);
        *(float*)(sm + pp * 512 + (nb4 ^ (((pp >> 2) & 3) << 6))) = v;
      }
    }
  __syncthreads();
  #pragma unroll
  for (int it = 0; it < 8; ++it) {
    int idx = it * 256 + tid;
    int pp = idx >> 5, ch = idx & 31;
    uint4 v = *(const uint4*)(sm + pp * 512 + ((ch * 16) ^ (((pp >> 2) & 3) << 6)));
    ntstore16((unsigned char*)out + (size_t)(p0 + pp) * 512 + ch * 16, v);
  }
}

extern "C" void kernel_launch(void* const* d_in, const int* in_sizes, int n_in,
                              void* d_out, int out_size, void* d_ws, size_t ws_size,
                              hipStream_t stream) {
  (void)in_sizes; (void)n_in; (void)out_size; (void)ws_size;
  const float* x         = (const float*)d_in[0];
  const float* mask      = (const float*)d_in[1];
  const float* w_p_in    = (const float*)d_in[2];
  const float* w_g_in    = (const float*)d_in[3];
  const float* w_p_out   = (const float*)d_in[4];
  const float* w_g_out   = (const float*)d_in[5];
  const float* norm_in_w = (const float*)d_in[6];
  const float* norm_in_b = (const float*)d_in[7];
  const float* norm_out_w= (const float*)d_in[8];
  const float* norm_out_b= (const float*)d_in[9];
  float* out = (float*)d_out;

  unsigned char* ws = (unsigned char*)d_ws;
  const size_t SLAB = (size_t)128 * PITCH;          // ~64.5 MiB per d-major buffer
  unsigned char* a_t    = ws;
  unsigned char* b_t    = ws + SLAB;
  unsigned char* t_buf  = ws + 2 * SLAB;
  unsigned short* xn_sw = (unsigned short*)(ws + 3 * SLAB);          // 64 MiB
  unsigned short* wprep = (unsigned short*)(ws + 3 * SLAB + (size_t)NP * 256); // 192 KiB

  kw_prep<<<384, 256, 0, stream>>>(w_p_in, w_g_in, w_g_out, w_p_out, wprep);
  kA_ln<<<4096, 256, 0, stream>>>(x, norm_in_w, norm_in_b, xn_sw);
  kB_gemm<<<8192, 256, 0, stream>>>(xn_sw, mask, wprep, a_t, b_t);
  k2_einsum<<<2048, 512, 0, stream>>>(a_t, b_t, t_buf);
  k3_out<<<4096, 256, 0, stream>>>(t_buf, xn_sw, wprep, norm_out_w, norm_out_b, out);
}

// Round 18
// 230.729 us; speedup vs baseline: 1.0087x; 1.0087x over previous
//
#include <hip/hip_runtime.h>
#include <hip/hip_bf16.h>
#include <math.h>

#define NN 512
#define DD 128
#define NP (NN*NN)   // 262144

// d-major slabs: skewed pitch 512KB + 4KB + 256B.
#define PITCH ((size_t)(NP * 2 + 4096 + 256))

typedef __attribute__((ext_vector_type(4))) float f32x4;
typedef __attribute__((ext_vector_type(8))) short bf16x8;
typedef __attribute__((ext_vector_type(4))) unsigned int u32x4;

__device__ __forceinline__ unsigned short f2bf(float f) {
  union { float f; unsigned u; } v; v.f = f;
  unsigned r = v.u + 0x7FFFu + ((v.u >> 16) & 1u);
  return (unsigned short)(r >> 16);
}
__device__ __forceinline__ float bf2f(unsigned short h) {
  union { unsigned u; float f; } v; v.u = ((unsigned)h) << 16;
  return v.f;
}
__device__ __forceinline__ float sigmoidf_(float x) {
  return __builtin_amdgcn_rcpf(1.0f + __expf(-x));
}
__device__ __forceinline__ unsigned pkbf2(float a, float b) {
  float2 t; t.x = a; t.y = b;
  __hip_bfloat162 h = __float22bfloat162_rn(t);
  unsigned r; __builtin_memcpy(&r, &h, 4); return r;
}
__device__ __forceinline__ void ntstore16(void* p, uint4 v) {
  u32x4 w; __builtin_memcpy(&w, &v, 16);
  __builtin_nontemporal_store(w, (u32x4*)p);
}

__device__ __forceinline__ void gll16(void* lds, const void* g) {
  __builtin_amdgcn_global_load_lds(
      (const __attribute__((address_space(1))) void*)g,
      (__attribute__((address_space(3))) void*)lds, 16, 0, 0);
}

// wprep byte-layout: P[256 cols] @0, G[256 cols] @65536, GO[128] @131072, PO[128] @163840
#define WP_P  0
#define WP_G  65536
#define WP_GO 131072
#define WP_PO 163840

__global__ __launch_bounds__(256) void kw_prep(const float* __restrict__ w_p_in,
    const float* __restrict__ w_g_in, const float* __restrict__ w_g_out,
    const float* __restrict__ w_p_out, unsigned short* __restrict__ wprep) {
  int idx = blockIdx.x * 256 + threadIdx.x;   // 0..98303
  int n, k, base; float v;
  if (idx < 32768)       { n = idx >> 7;          k = idx & 127; v = w_p_in[k * 256 + n];  base = WP_P; }
  else if (idx < 65536)  { int e = idx - 32768;  n = e >> 7; k = e & 127; v = w_g_in[k * 256 + n];  base = WP_G; }
  else if (idx < 81920)  { int e = idx - 65536;  n = e >> 7; k = e & 127; v = w_g_out[k * 128 + n]; base = WP_GO; }
  else                   { int e = idx - 81920;  n = e >> 7; k = e & 127; v = w_p_out[k * 128 + n]; base = WP_PO; }
  int dst = base + n * 256 + ((2 * k) ^ ((n & 7) << 4));
  wprep[dst >> 1] = f2bf(v);
}

// ---------------- KA: layernorm(x) -> xn_sw (PRE-SWIZZLED global bf16 image) --
__global__ __launch_bounds__(256) void kA_ln(const float* __restrict__ x,
    const float* __restrict__ nw, const float* __restrict__ nb,
    unsigned short* __restrict__ xn_sw) {
  const int tid = threadIdx.x;
  const int l16 = tid & 15, rsub = tid >> 4;
  const int row0 = blockIdx.x * 64;
  const float4 wv0 = *(const float4*)(nw + l16 * 8);
  const float4 wv1 = *(const float4*)(nw + l16 * 8 + 4);
  const float4 bv0 = *(const float4*)(nb + l16 * 8);
  const float4 bv1 = *(const float4*)(nb + l16 * 8 + 4);
  #pragma unroll
  for (int rnd = 0; rnd < 4; ++rnd) {
    int r = row0 + rnd * 16 + rsub;
    const f32x4* xr = (const f32x4*)(x + (size_t)r * DD + l16 * 8);
    f32x4 a0 = __builtin_nontemporal_load(xr);
    f32x4 a1 = __builtin_nontemporal_load(xr + 1);
    float4 v0 = *(float4*)&a0, v1 = *(float4*)&a1;
    float s = v0.x + v0.y + v0.z + v0.w + v1.x + v1.y + v1.z + v1.w;
    float q = v0.x*v0.x + v0.y*v0.y + v0.z*v0.z + v0.w*v0.w
            + v1.x*v1.x + v1.y*v1.y + v1.z*v1.z + v1.w*v1.w;
    #pragma unroll
    for (int m = 8; m; m >>= 1) { s += __shfl_xor(s, m); q += __shfl_xor(q, m); }
    float mean = s * (1.0f / DD);
    float var = q * (1.0f / DD) - mean * mean;
    float rstd = rsqrtf(var + 1e-5f);
    uint4 pk;
    pk.x = pkbf2((v0.x - mean) * rstd * wv0.x + bv0.x, (v0.y - mean) * rstd * wv0.y + bv0.y);
    pk.y = pkbf2((v0.z - mean) * rstd * wv0.z + bv0.z, (v0.w - mean) * rstd * wv0.w + bv0.w);
    pk.z = pkbf2((v1.x - mean) * rstd * wv1.x + bv1.x, (v1.y - mean) * rstd * wv1.y + bv1.y);
    pk.w = pkbf2((v1.z - mean) * rstd * wv1.z + bv1.z, (v1.w - mean) * rstd * wv1.w + bv1.w);
    *(uint4*)((unsigned char*)xn_sw + (size_t)r * 256 + ((l16 * 16) ^ ((r & 7) << 4))) = pk;
  }
}

// ---------------- KB: ONE gated GEMM pass per block (grid 8192, 1D) -----------
__global__ __launch_bounds__(256) void kB_gemm(
    const unsigned short* __restrict__ xn_sw, const float* __restrict__ mask,
    const unsigned short* __restrict__ wprep,
    unsigned char* __restrict__ a_t, unsigned char* __restrict__ b_t) {
  const int bid = blockIdx.x;
  const int q = (bid >> 3) & 3;                       // 0..3
  const int rt = (bid & 7) | ((bid >> 5) << 3);       // row-tile 0..2047
  const int row0 = rt * 128;
  const int i_idx = row0 >> 9;           // i coordinate
  const int kb = (row0 & 511) >> 7;      // k-granule 0..3
  const int tid = threadIdx.x, lane = tid & 63, wv = tid >> 6;
  const int wr = wv >> 1, wc = wv & 1;
  __shared__ __align__(16) unsigned char sxn[32768];   // staging image, then epilogue
  __shared__ float smask[128];

  const unsigned char* wp = (const unsigned char*)wprep;

  // prefetch weights into registers (independent of staging)
  bf16x8 wP[4][2], wG[4][2];
  #pragma unroll
  for (int ks = 0; ks < 4; ++ks) {
    int kbb = ks * 64 + (lane >> 4) * 16;
    #pragma unroll
    for (int ni = 0; ni < 2; ++ni) {
      int n = q * 64 + wc * 32 + ni * 16 + (lane & 15);
      int off = n * 256 + (kbb ^ ((n & 7) << 4));
      wP[ks][ni] = *(const bf16x8*)(wp + WP_P + off);
      wG[ks][ni] = *(const bf16x8*)(wp + WP_G + off);
    }
  }

  #pragma unroll
  for (int it = 0; it < 8; ++it) {
    int o = it * 4096 + tid * 16;
    gll16(sxn + o, (const unsigned char*)xn_sw + (size_t)row0 * 256 + o);
  }
  if (tid < 128) smask[tid] = mask[row0 + tid];
  __syncthreads();

  f32x4 acc[4][4] = {};   // ni 0,1 = p ; ni 2,3 = g (same cols)
  #pragma unroll
  for (int ks = 0; ks < 4; ++ks) {
    int kbb = ks * 64 + (lane >> 4) * 16;
    bf16x8 af[4];
    #pragma unroll
    for (int mi = 0; mi < 4; ++mi) {
      int r = wr * 64 + mi * 16 + (lane & 15);
      af[mi] = *(const bf16x8*)(sxn + r * 256 + (kbb ^ ((r & 7) << 4)));
    }
    #pragma unroll
    for (int mi = 0; mi < 4; ++mi)
      #pragma unroll
      for (int ni = 0; ni < 2; ++ni) {
        acc[mi][ni]     = __builtin_amdgcn_mfma_f32_16x16x32_bf16(af[mi], wP[ks][ni], acc[mi][ni], 0, 0, 0);
        acc[mi][ni + 2] = __builtin_amdgcn_mfma_f32_16x16x32_bf16(af[mi], wG[ks][ni], acc[mi][ni + 2], 0, 0, 0);
      }
  }

  __syncthreads();   // all sxn reads done; buffer reusable for epilogue
  #pragma unroll
  for (int mi = 0; mi < 4; ++mi) {
    int rq = wr * 64 + mi * 16 + (lane >> 4) * 4;
    float mk0 = smask[rq], mk1 = smask[rq + 1], mk2 = smask[rq + 2], mk3 = smask[rq + 3];
    #pragma unroll
    for (int ni = 0; ni < 2; ++ni) {
      int drel = wc * 32 + ni * 16 + (lane & 15);
      uint2 pk;
      pk.x = pkbf2(acc[mi][ni][0] * sigmoidf_(acc[mi][ni + 2][0]) * mk0,
                   acc[mi][ni][1] * sigmoidf_(acc[mi][ni + 2][1]) * mk1);
      pk.y = pkbf2(acc[mi][ni][2] * sigmoidf_(acc[mi][ni + 2][2]) * mk2,
                   acc[mi][ni][3] * sigmoidf_(acc[mi][ni + 2][3]) * mk3);
      *(uint2*)(sxn + drel * 256 + ((rq * 2) ^ ((drel & 7) << 4))) = pk;
    }
  }
  __syncthreads();
  unsigned char* dst = (q < 2) ? a_t : b_t;
  const int dmin = (q & 1) * 64;
  #pragma unroll
  for (int it = 0; it < 4; ++it) {
    int idx = it * 256 + tid;
    int dr = idx >> 4, ch = idx & 15;
    uint4 v = *(const uint4*)(sxn + dr * 256 + ((ch * 16) ^ ((dr & 7) << 4)));
    ntstore16(dst + (size_t)(dmin + dr) * PITCH + (size_t)kb * 131072
                  + (size_t)i_idx * 256 + ch * 16, v);
  }
}

// ---------------- K2: per-d GEMM, 512 threads, counted-vmcnt pipeline ---------
// T3/T4: issue next tile -> s_waitcnt vmcnt(4) (keeps next tile in flight) ->
// raw s_barrier -> ds_read+MFMA -> raw s_barrier (reads-done, NO drain).
// t output layout: byte(d,i,j) = ((i*512+j)>>6)*16384 + d*128 + (j&63)*2.
__global__ __launch_bounds__(512) void k2_einsum(
    const unsigned char* __restrict__ a_t, const unsigned char* __restrict__ b_t,
    unsigned char* __restrict__ t_out) {
  int bid = blockIdx.x;
  int wg = (bid & 7) * 256 + (bid >> 3);   // XCD swizzle (2048 % 8 == 0, bijective)
  int d = wg >> 4;
  int tile = wg & 15;
  int i0 = (tile >> 2) * 128, j0 = (tile & 3) * 128;
  const int tid = threadIdx.x, lane = tid & 63, wv = tid >> 6;  // wave 0..7
  const int wr = wv >> 1, wc = wv & 1;    // wr 0..3 (32-row strips), wc 0..1 (64-col)
  __shared__ __align__(16) unsigned char smem[65536];
  unsigned char* sA = smem;            // [2][16384]
  unsigned char* sB = smem + 32768;    // [2][16384]
  const unsigned char* Abase = a_t + (size_t)d * PITCH;
  const unsigned char* Bbase = b_t + (size_t)d * PITCH;

  int sil[2], sga[2];
  #pragma unroll
  for (int j = 0; j < 2; ++j) {
    int o = j * 8192 + tid * 16;
    int il = o >> 7, c = (o >> 4) & 7;
    sil[j] = o;
    sga[j] = il * 256 + ((c ^ (il & 7)) << 4);
  }

  f32x4 acc[2][4] = {};
  // prologue: issue tile 0 into buf 0 (4 loads/thread), do NOT drain yet
  #pragma unroll
  for (int j = 0; j < 2; ++j) {
    gll16(sA + sil[j], Abase + (size_t)i0 * 256 + sga[j]);
    gll16(sB + sil[j], Bbase + (size_t)j0 * 256 + sga[j]);
  }

  #pragma unroll
  for (int t = 0; t < 8; ++t) {
    if (t < 7) {
      int tn = t + 1;
      size_t koff = (size_t)(tn >> 1) * 131072 + (size_t)(tn & 1) * 128;
      int nb_ = (tn & 1) * 16384;
      #pragma unroll
      for (int j = 0; j < 2; ++j) {
        gll16(sA + nb_ + sil[j], Abase + koff + (size_t)i0 * 256 + sga[j]);
        gll16(sB + nb_ + sil[j], Bbase + koff + (size_t)j0 * 256 + sga[j]);
      }
      asm volatile("s_waitcnt vmcnt(4)" ::: "memory");   // tile t done; t+1 in flight
    } else {
      asm volatile("s_waitcnt vmcnt(0)" ::: "memory");   // last tile: full drain
    }
    __builtin_amdgcn_sched_barrier(0);
    __builtin_amdgcn_s_barrier();                        // tile t visible to all waves
    int cb = (t & 1) * 16384;
    #pragma unroll
    for (int ks2 = 0; ks2 < 2; ++ks2) {
      bf16x8 af[2], bfr[4];
      int cfrag = ks2 * 4 + (lane >> 4);
      #pragma unroll
      for (int mi = 0; mi < 2; ++mi) {
        int r = wr * 32 + mi * 16 + (lane & 15);
        af[mi] = *(const bf16x8*)(sA + cb + r * 128 + ((cfrag ^ (r & 7)) << 4));
      }
      #pragma unroll
      for (int ni = 0; ni < 4; ++ni) {
        int r = wc * 64 + ni * 16 + (lane & 15);
        bfr[ni] = *(const bf16x8*)(sB + cb + r * 128 + ((cfrag ^ (r & 7)) << 4));
      }
      #pragma unroll
      for (int mi = 0; mi < 2; ++mi)
        #pragma unroll
        for (int ni = 0; ni < 4; ++ni)
          acc[mi][ni] = __builtin_amdgcn_mfma_f32_16x16x32_bf16(af[mi], bfr[ni], acc[mi][ni], 0, 0, 0);
    }
    __builtin_amdgcn_sched_barrier(0);
    __builtin_amdgcn_s_barrier();   // reads of buf[t&1] done (no vmcnt drain)
  }

  // epilogue: stage [128 i][256B j] bf16 (XOR-swizzled) in smem, dense nt stores
  #pragma unroll
  for (int mi = 0; mi < 2; ++mi)
    #pragma unroll
    for (int j = 0; j < 4; ++j) {
      int il = wr * 32 + mi * 16 + (lane >> 4) * 4 + j;
      #pragma unroll
      for (int ni = 0; ni < 4; ++ni) {
        int jl = wc * 64 + ni * 16 + (lane & 15);
        *(unsigned short*)(smem + il * 256 + ((jl * 2) ^ ((il & 7) << 4))) = f2bf(acc[mi][ni][j]);
      }
    }
  __syncthreads();
  #pragma unroll
  for (int rr = 0; rr < 4; ++rr) {
    int u = rr * 512 + tid;
    int il = u >> 4, sub = u & 15;
    int jg = sub >> 3, cc = sub & 7;
    uint4 v = *(const uint4*)(smem + il * 256 + ((sub * 16) ^ ((il & 7) << 4)));
    ntstore16(t_out + ((size_t)(i0 + il) * 8 + (j0 >> 6) + jg) * 16384
                    + (size_t)d * 128 + cc * 16, v);
  }
}

// ---------------- K3: LN over d + (tn @ w_p_out) * sigmoid(xn @ w_g_out) ------
__global__ __launch_bounds__(256) void k3_out(
    const unsigned char* __restrict__ t_in, const unsigned short* __restrict__ xn_sw,
    const unsigned short* __restrict__ wprep,
    const float* __restrict__ now, const float* __restrict__ nob,
    float* __restrict__ out) {
  const int p0 = blockIdx.x * 64;
  const int tid = threadIdx.x, lane = tid & 63, wv = tid >> 6;
  const int wr = wv >> 1, wc = wv & 1;
  __shared__ __align__(16) unsigned char sm[49152];
  unsigned short* sT = (unsigned short*)sm;        // [d][p] bf16, 16KB
  unsigned char* sTN = sm + 16384;                 // [p][d] swizzled, 16KB
  unsigned char* sxn = sm + 32768;                 // xn rows swizzled, 16KB
  __shared__ float ps[4][64], pq[4][64], smean[64], srstd[64];

  #pragma unroll
  for (int it = 0; it < 4; ++it) {
    int o = it * 4096 + tid * 16;
    gll16((unsigned char*)sT + o, t_in + (size_t)blockIdx.x * 16384 + o);
  }
  #pragma unroll
  for (int it = 0; it < 4; ++it) {
    int o = it * 4096 + tid * 16;
    gll16(sxn + o, (const unsigned char*)xn_sw + (size_t)p0 * 256 + o);
  }
  __syncthreads();
  const int p = tid & 63, dh = tid >> 6;
  {
    float s = 0.f, q = 0.f;
    #pragma unroll
    for (int dd = 0; dd < 32; ++dd) {
      float v = bf2f(sT[(dh * 32 + dd) * 64 + p]);
      s += v; q += v * v;
    }
    ps[dh][p] = s; pq[dh][p] = q;
  }
  __syncthreads();
  if (tid < 64) {
    float s = ps[0][tid] + ps[1][tid] + ps[2][tid] + ps[3][tid];
    float q = pq[0][tid] + pq[1][tid] + pq[2][tid] + pq[3][tid];
    float mean = s * (1.0f / 128.0f);
    float var = q * (1.0f / 128.0f) - mean * mean;
    smean[tid] = mean; srstd[tid] = rsqrtf(var + 1e-5f);
  }
  __syncthreads();
  {
    float mean = smean[p], rstd = srstd[p];
    #pragma unroll
    for (int e = 0; e < 16; ++e) {
      int d0 = dh * 32 + e * 2;
      float v0 = (bf2f(sT[d0 * 64 + p]) - mean) * rstd * now[d0] + nob[d0];
      float v1 = (bf2f(sT[(d0 + 1) * 64 + p]) - mean) * rstd * now[d0 + 1] + nob[d0 + 1];
      unsigned pack = pkbf2(v0, v1);
      *(unsigned*)(sTN + p * 256 + ((d0 * 2) ^ ((p & 7) << 4))) = pack;
    }
  }
  __syncthreads();
  f32x4 accP[2][4] = {}, accG[2][4] = {};
  const unsigned char* wpo = (const unsigned char*)wprep + WP_PO;
  const unsigned char* wgo = (const unsigned char*)wprep + WP_GO;
  #pragma unroll
  for (int ks = 0; ks < 4; ++ks) {
    int kbb = ks * 64 + (lane >> 4) * 16;
    bf16x8 af[2], ag[2], bP[4], bG[4];
    #pragma unroll
    for (int mi = 0; mi < 2; ++mi) {
      int r = wr * 32 + mi * 16 + (lane & 15);
      int off = r * 256 + (kbb ^ ((r & 7) << 4));
      af[mi] = *(const bf16x8*)(sTN + off);
      ag[mi] = *(const bf16x8*)(sxn + off);
    }
    #pragma unroll
    for (int ni = 0; ni < 4; ++ni) {
      int n = wc * 64 + ni * 16 + (lane & 15);
      int off = n * 256 + (kbb ^ ((n & 7) << 4));
      bP[ni] = *(const bf16x8*)(wpo + off);
      bG[ni] = *(const bf16x8*)(wgo + off);
    }
    #pragma unroll
    for (int mi = 0; mi < 2; ++mi)
      #pragma unroll
      for (int ni = 0; ni < 4; ++ni) {
        accP[mi][ni] = __builtin_amdgcn_mfma_f32_16x16x32_bf16(af[mi], bP[ni], accP[mi][ni], 0, 0, 0);
        accG[mi][ni] = __builtin_amdgcn_mfma_f32_16x16x32_bf16(ag[mi], bG[ni], accG[mi][ni], 0, 0, 0);
      }
  }
  // epilogue: stage f32 [64 p][512B], 64B-window XOR by (p>>2)&3 -> dense nt stores
  __syncthreads();
  #pragma unroll
  for (int mi = 0; mi < 2; ++mi)
    #pragma unroll
    for (int ni = 0; ni < 4; ++ni) {
      int nb4 = (wc * 256 + ni * 64 + (lane & 15) * 4);
      int prow = wr * 32 + mi * 16 + (lane >> 4) * 4;
      #pragma unroll
      for (int j = 0; j < 4; ++j) {
        int pp = prow + j;
        float v = accP[mi][ni][j] * sigmoidf_(accG[mi][ni][j]);
        *(float*)(sm + pp * 512 + (nb4 ^ (((pp >> 2) & 3) << 6))) = v;
      }
    }
  __syncthreads();
  #pragma unroll
  for (int it = 0; it < 8; ++it) {
    int idx = it * 256 + tid;
    int pp = idx >> 5, ch = idx & 31;
    uint4 v = *(const uint4*)(sm + pp * 512 + ((ch * 16) ^ (((pp >> 2) & 3) << 6)));
    ntstore16((unsigned char*)out + (size_t)(p0 + pp) * 512 + ch * 16, v);
  }
}

extern "C" void kernel_launch(void* const* d_in, const int* in_sizes, int n_in,
                              void* d_out, int out_size, void* d_ws, size_t ws_size,
                              hipStream_t stream) {
  (void)in_sizes; (void)n_in; (void)out_size; (void)ws_size;
  const float* x         = (const float*)d_in[0];
  const float* mask      = (const float*)d_in[1];
  const float* w_p_in    = (const float*)d_in[2];
  const float* w_g_in    = (const float*)d_in[3];
  const float* w_p_out   = (const float*)d_in[4];
  const float* w_g_out   = (const float*)d_in[5];
  const float* norm_in_w = (const float*)d_in[6];
  const float* norm_in_b = (const float*)d_in[7];
  const float* norm_out_w= (const float*)d_in[8];
  const float* norm_out_b= (const float*)d_in[9];
  float* out = (float*)d_out;

  unsigned char* ws = (unsigned char*)d_ws;
  const size_t SLAB = (size_t)128 * PITCH;          // ~64.5 MiB per d-major buffer
  unsigned char* a_t    = ws;
  unsigned char* b_t    = ws + SLAB;
  unsigned char* t_buf  = ws + 2 * SLAB;
  unsigned short* xn_sw = (unsigned short*)(ws + 3 * SLAB);          // 64 MiB
  unsigned short* wprep = (unsigned short*)(ws + 3 * SLAB + (size_t)NP * 256); // 192 KiB

  kw_prep<<<384, 256, 0, stream>>>(w_p_in, w_g_in, w_g_out, w_p_out, wprep);
  kA_ln<<<4096, 256, 0, stream>>>(x, norm_in_w, norm_in_b, xn_sw);
  kB_gemm<<<8192, 256, 0, stream>>>(xn_sw, mask, wprep, a_t, b_t);
  k2_einsum<<<2048, 512, 0, stream>>>(a_t, b_t, t_buf);
  k3_out<<<4096, 256, 0, stream>>>(t_buf, xn_sw, wprep, norm_out_w, norm_out_b, out);
}

// Round 19
// 228.355 us; speedup vs baseline: 1.0192x; 1.0104x over previous
//
#include <hip/hip_runtime.h>
#include <hip/hip_bf16.h>
#include <math.h>

#define NN 512
#define DD 128
#define NP (NN*NN)   // 262144

// d-major slabs: skewed pitch 512KB + 4KB + 256B.
#define PITCH ((size_t)(NP * 2 + 4096 + 256))

typedef __attribute__((ext_vector_type(4))) float f32x4;
typedef __attribute__((ext_vector_type(8))) short bf16x8;
typedef __attribute__((ext_vector_type(4))) unsigned int u32x4;

__device__ __forceinline__ unsigned short f2bf(float f) {
  union { float f; unsigned u; } v; v.f = f;
  unsigned r = v.u + 0x7FFFu + ((v.u >> 16) & 1u);
  return (unsigned short)(r >> 16);
}
__device__ __forceinline__ float bf2f(unsigned short h) {
  union { unsigned u; float f; } v; v.u = ((unsigned)h) << 16;
  return v.f;
}
__device__ __forceinline__ float sigmoidf_(float x) {
  return __builtin_amdgcn_rcpf(1.0f + __expf(-x));
}
__device__ __forceinline__ unsigned pkbf2(float a, float b) {
  float2 t; t.x = a; t.y = b;
  __hip_bfloat162 h = __float22bfloat162_rn(t);
  unsigned r; __builtin_memcpy(&r, &h, 4); return r;
}
__device__ __forceinline__ void ntstore16(void* p, uint4 v) {
  u32x4 w; __builtin_memcpy(&w, &v, 16);
  __builtin_nontemporal_store(w, (u32x4*)p);
}

__device__ __forceinline__ void gll16(void* lds, const void* g) {
  __builtin_amdgcn_global_load_lds(
      (const __attribute__((address_space(1))) void*)g,
      (__attribute__((address_space(3))) void*)lds, 16, 0, 0);
}

// wprep byte-layout: P[256 cols] @0, G[256 cols] @65536, GO[128] @131072, PO[128] @163840
#define WP_P  0
#define WP_G  65536
#define WP_GO 131072
#define WP_PO 163840

__global__ __launch_bounds__(256) void kw_prep(const float* __restrict__ w_p_in,
    const float* __restrict__ w_g_in, const float* __restrict__ w_g_out,
    const float* __restrict__ w_p_out, unsigned short* __restrict__ wprep) {
  int idx = blockIdx.x * 256 + threadIdx.x;   // 0..98303
  int n, k, base; float v;
  if (idx < 32768)       { n = idx >> 7;          k = idx & 127; v = w_p_in[k * 256 + n];  base = WP_P; }
  else if (idx < 65536)  { int e = idx - 32768;  n = e >> 7; k = e & 127; v = w_g_in[k * 256 + n];  base = WP_G; }
  else if (idx < 81920)  { int e = idx - 65536;  n = e >> 7; k = e & 127; v = w_g_out[k * 128 + n]; base = WP_GO; }
  else                   { int e = idx - 81920;  n = e >> 7; k = e & 127; v = w_p_out[k * 128 + n]; base = WP_PO; }
  int dst = base + n * 256 + ((2 * k) ^ ((n & 7) << 4));
  wprep[dst >> 1] = f2bf(v);
}

// ---------------- KA: layernorm(x) -> xn_sw (PRE-SWIZZLED global bf16 image) --
__global__ __launch_bounds__(256) void kA_ln(const float* __restrict__ x,
    const float* __restrict__ nw, const float* __restrict__ nb,
    unsigned short* __restrict__ xn_sw) {
  const int tid = threadIdx.x;
  const int l16 = tid & 15, rsub = tid >> 4;
  const int row0 = blockIdx.x * 64;
  const float4 wv0 = *(const float4*)(nw + l16 * 8);
  const float4 wv1 = *(const float4*)(nw + l16 * 8 + 4);
  const float4 bv0 = *(const float4*)(nb + l16 * 8);
  const float4 bv1 = *(const float4*)(nb + l16 * 8 + 4);
  #pragma unroll
  for (int rnd = 0; rnd < 4; ++rnd) {
    int r = row0 + rnd * 16 + rsub;
    const f32x4* xr = (const f32x4*)(x + (size_t)r * DD + l16 * 8);
    f32x4 a0 = __builtin_nontemporal_load(xr);
    f32x4 a1 = __builtin_nontemporal_load(xr + 1);
    float4 v0 = *(float4*)&a0, v1 = *(float4*)&a1;
    float s = v0.x + v0.y + v0.z + v0.w + v1.x + v1.y + v1.z + v1.w;
    float q = v0.x*v0.x + v0.y*v0.y + v0.z*v0.z + v0.w*v0.w
            + v1.x*v1.x + v1.y*v1.y + v1.z*v1.z + v1.w*v1.w;
    #pragma unroll
    for (int m = 8; m; m >>= 1) { s += __shfl_xor(s, m); q += __shfl_xor(q, m); }
    float mean = s * (1.0f / DD);
    float var = q * (1.0f / DD) - mean * mean;
    float rstd = rsqrtf(var + 1e-5f);
    uint4 pk;
    pk.x = pkbf2((v0.x - mean) * rstd * wv0.x + bv0.x, (v0.y - mean) * rstd * wv0.y + bv0.y);
    pk.y = pkbf2((v0.z - mean) * rstd * wv0.z + bv0.z, (v0.w - mean) * rstd * wv0.w + bv0.w);
    pk.z = pkbf2((v1.x - mean) * rstd * wv1.x + bv1.x, (v1.y - mean) * rstd * wv1.y + bv1.y);
    pk.w = pkbf2((v1.z - mean) * rstd * wv1.z + bv1.z, (v1.w - mean) * rstd * wv1.w + bv1.w);
    *(uint4*)((unsigned char*)xn_sw + (size_t)r * 256 + ((l16 * 16) ^ ((r & 7) << 4))) = pk;
  }
}

// ---------------- KB: ONE gated GEMM pass per block (grid 8192, 1D) -----------
// NO A-staging: MFMA A-fragments load DIRECTLY from the pre-swizzled, L2-hot
// xn_sw image (R15 remap keeps it resident). Removes 8 gll16 + 16 ds_read +
// the pre-MFMA drain barrier. LDS = 16KB epilogue buffer; ONE barrier/block.
// Mask in per-lane registers. Store layout (k-granule) unchanged.
__global__ __launch_bounds__(256) void kB_gemm(
    const unsigned short* __restrict__ xn_sw, const float* __restrict__ mask,
    const unsigned short* __restrict__ wprep,
    unsigned char* __restrict__ a_t, unsigned char* __restrict__ b_t) {
  const int bid = blockIdx.x;
  const int q = (bid >> 3) & 3;                       // 0..3
  const int rt = (bid & 7) | ((bid >> 5) << 3);       // row-tile 0..2047
  const int row0 = rt * 128;
  const int i_idx = row0 >> 9;           // i coordinate
  const int kb = (row0 & 511) >> 7;      // k-granule 0..3
  const int tid = threadIdx.x, lane = tid & 63, wv = tid >> 6;
  const int wr = wv >> 1, wc = wv & 1;
  __shared__ __align__(16) unsigned char sepi[16384];  // epilogue stage only

  const unsigned char* wp = (const unsigned char*)wprep;
  const unsigned char* xb = (const unsigned char*)xn_sw;

  // mask: per-lane registers (rows rq..rq+3 per mi)
  float4 mk[4];
  #pragma unroll
  for (int mi = 0; mi < 4; ++mi)
    mk[mi] = *(const float4*)(mask + row0 + wr * 64 + mi * 16 + (lane >> 4) * 4);

  // weights into registers (L2-hot)
  bf16x8 wP[4][2], wG[4][2];
  #pragma unroll
  for (int ks = 0; ks < 4; ++ks) {
    int kbb = ks * 64 + (lane >> 4) * 16;
    #pragma unroll
    for (int ni = 0; ni < 2; ++ni) {
      int n = q * 64 + wc * 32 + ni * 16 + (lane & 15);
      int off = n * 256 + (kbb ^ ((n & 7) << 4));
      wP[ks][ni] = *(const bf16x8*)(wp + WP_P + off);
      wG[ks][ni] = *(const bf16x8*)(wp + WP_G + off);
    }
  }

  f32x4 acc[4][4] = {};   // ni 0,1 = p ; ni 2,3 = g (same cols)
  #pragma unroll
  for (int ks = 0; ks < 4; ++ks) {
    int kbb = ks * 64 + (lane >> 4) * 16;
    bf16x8 af[4];
    #pragma unroll
    for (int mi = 0; mi < 4; ++mi) {
      int r = wr * 64 + mi * 16 + (lane & 15);
      af[mi] = *(const bf16x8*)(xb + (size_t)(row0 + r) * 256 + (kbb ^ ((r & 7) << 4)));
    }
    #pragma unroll
    for (int mi = 0; mi < 4; ++mi)
      #pragma unroll
      for (int ni = 0; ni < 2; ++ni) {
        acc[mi][ni]     = __builtin_amdgcn_mfma_f32_16x16x32_bf16(af[mi], wP[ks][ni], acc[mi][ni], 0, 0, 0);
        acc[mi][ni + 2] = __builtin_amdgcn_mfma_f32_16x16x32_bf16(af[mi], wG[ks][ni], acc[mi][ni + 2], 0, 0, 0);
      }
  }

  // epilogue: gated pack into sepi, ONE barrier, 256B-dense nt stores
  #pragma unroll
  for (int mi = 0; mi < 4; ++mi) {
    int rq = wr * 64 + mi * 16 + (lane >> 4) * 4;
    const float* m = (const float*)&mk[mi];
    #pragma unroll
    for (int ni = 0; ni < 2; ++ni) {
      int drel = wc * 32 + ni * 16 + (lane & 15);
      uint2 pk;
      pk.x = pkbf2(acc[mi][ni][0] * sigmoidf_(acc[mi][ni + 2][0]) * m[0],
                   acc[mi][ni][1] * sigmoidf_(acc[mi][ni + 2][1]) * m[1]);
      pk.y = pkbf2(acc[mi][ni][2] * sigmoidf_(acc[mi][ni + 2][2]) * m[2],
                   acc[mi][ni][3] * sigmoidf_(acc[mi][ni + 2][3]) * m[3]);
      *(uint2*)(sepi + drel * 256 + ((rq * 2) ^ ((drel & 7) << 4))) = pk;
    }
  }
  __syncthreads();
  unsigned char* dst = (q < 2) ? a_t : b_t;
  const int dmin = (q & 1) * 64;
  #pragma unroll
  for (int it = 0; it < 4; ++it) {
    int idx = it * 256 + tid;
    int dr = idx >> 4, ch = idx & 15;
    uint4 v = *(const uint4*)(sepi + dr * 256 + ((ch * 16) ^ ((dr & 7) << 4)));
    ntstore16(dst + (size_t)(dmin + dr) * PITCH + (size_t)kb * 131072
                  + (size_t)i_idx * 256 + ch * 16, v);
  }
}

// ---------------- K2: per-d GEMM, 512 threads, counted-vmcnt pipeline ---------
__global__ __launch_bounds__(512) void k2_einsum(
    const unsigned char* __restrict__ a_t, const unsigned char* __restrict__ b_t,
    unsigned char* __restrict__ t_out) {
  int bid = blockIdx.x;
  int wg = (bid & 7) * 256 + (bid >> 3);   // XCD swizzle (2048 % 8 == 0, bijective)
  int d = wg >> 4;
  int tile = wg & 15;
  int i0 = (tile >> 2) * 128, j0 = (tile & 3) * 128;
  const int tid = threadIdx.x, lane = tid & 63, wv = tid >> 6;  // wave 0..7
  const int wr = wv >> 1, wc = wv & 1;    // wr 0..3 (32-row strips), wc 0..1 (64-col)
  __shared__ __align__(16) unsigned char smem[65536];
  unsigned char* sA = smem;            // [2][16384]
  unsigned char* sB = smem + 32768;    // [2][16384]
  const unsigned char* Abase = a_t + (size_t)d * PITCH;
  const unsigned char* Bbase = b_t + (size_t)d * PITCH;

  int sil[2], sga[2];
  #pragma unroll
  for (int j = 0; j < 2; ++j) {
    int o = j * 8192 + tid * 16;
    int il = o >> 7, c = (o >> 4) & 7;
    sil[j] = o;
    sga[j] = il * 256 + ((c ^ (il & 7)) << 4);
  }

  f32x4 acc[2][4] = {};
  // prologue: issue tile 0 into buf 0 (4 loads/thread), do NOT drain yet
  #pragma unroll
  for (int j = 0; j < 2; ++j) {
    gll16(sA + sil[j], Abase + (size_t)i0 * 256 + sga[j]);
    gll16(sB + sil[j], Bbase + (size_t)j0 * 256 + sga[j]);
  }

  #pragma unroll
  for (int t = 0; t < 8; ++t) {
    if (t < 7) {
      int tn = t + 1;
      size_t koff = (size_t)(tn >> 1) * 131072 + (size_t)(tn & 1) * 128;
      int nb_ = (tn & 1) * 16384;
      #pragma unroll
      for (int j = 0; j < 2; ++j) {
        gll16(sA + nb_ + sil[j], Abase + koff + (size_t)i0 * 256 + sga[j]);
        gll16(sB + nb_ + sil[j], Bbase + koff + (size_t)j0 * 256 + sga[j]);
      }
      asm volatile("s_waitcnt vmcnt(4)" ::: "memory");   // tile t done; t+1 in flight
    } else {
      asm volatile("s_waitcnt vmcnt(0)" ::: "memory");   // last tile: full drain
    }
    __builtin_amdgcn_sched_barrier(0);
    __builtin_amdgcn_s_barrier();                        // tile t visible to all waves
    int cb = (t & 1) * 16384;
    #pragma unroll
    for (int ks2 = 0; ks2 < 2; ++ks2) {
      bf16x8 af[2], bfr[4];
      int cfrag = ks2 * 4 + (lane >> 4);
      #pragma unroll
      for (int mi = 0; mi < 2; ++mi) {
        int r = wr * 32 + mi * 16 + (lane & 15);
        af[mi] = *(const bf16x8*)(sA + cb + r * 128 + ((cfrag ^ (r & 7)) << 4));
      }
      #pragma unroll
      for (int ni = 0; ni < 4; ++ni) {
        int r = wc * 64 + ni * 16 + (lane & 15);
        bfr[ni] = *(const bf16x8*)(sB + cb + r * 128 + ((cfrag ^ (r & 7)) << 4));
      }
      #pragma unroll
      for (int mi = 0; mi < 2; ++mi)
        #pragma unroll
        for (int ni = 0; ni < 4; ++ni)
          acc[mi][ni] = __builtin_amdgcn_mfma_f32_16x16x32_bf16(af[mi], bfr[ni], acc[mi][ni], 0, 0, 0);
    }
    __builtin_amdgcn_sched_barrier(0);
    __builtin_amdgcn_s_barrier();   // reads of buf[t&1] done (no vmcnt drain)
  }

  // epilogue: stage [128 i][256B j] bf16 (XOR-swizzled) in smem, dense nt stores
  #pragma unroll
  for (int mi = 0; mi < 2; ++mi)
    #pragma unroll
    for (int j = 0; j < 4; ++j) {
      int il = wr * 32 + mi * 16 + (lane >> 4) * 4 + j;
      #pragma unroll
      for (int ni = 0; ni < 4; ++ni) {
        int jl = wc * 64 + ni * 16 + (lane & 15);
        *(unsigned short*)(smem + il * 256 + ((jl * 2) ^ ((il & 7) << 4))) = f2bf(acc[mi][ni][j]);
      }
    }
  __syncthreads();
  #pragma unroll
  for (int rr = 0; rr < 4; ++rr) {
    int u = rr * 512 + tid;
    int il = u >> 4, sub = u & 15;
    int jg = sub >> 3, cc = sub & 7;
    uint4 v = *(const uint4*)(smem + il * 256 + ((sub * 16) ^ ((il & 7) << 4)));
    ntstore16(t_out + ((size_t)(i0 + il) * 8 + (j0 >> 6) + jg) * 16384
                    + (size_t)d * 128 + cc * 16, v);
  }
}

// ---------------- K3: LN over d + (tn @ w_p_out) * sigmoid(xn @ w_g_out) ------
__global__ __launch_bounds__(256) void k3_out(
    const unsigned char* __restrict__ t_in, const unsigned short* __restrict__ xn_sw,
    const unsigned short* __restrict__ wprep,
    const float* __restrict__ now, const float* __restrict__ nob,
    float* __restrict__ out) {
  const int p0 = blockIdx.x * 64;
  const int tid = threadIdx.x, lane = tid & 63, wv = tid >> 6;
  const int wr = wv >> 1, wc = wv & 1;
  __shared__ __align__(16) unsigned char sm[49152];
  unsigned short* sT = (unsigned short*)sm;        // [d][p] bf16, 16KB
  unsigned char* sTN = sm + 16384;                 // [p][d] swizzled, 16KB
  unsigned char* sxn = sm + 32768;                 // xn rows swizzled, 16KB
  __shared__ float ps[4][64], pq[4][64], smean[64], srstd[64];

  #pragma unroll
  for (int it = 0; it < 4; ++it) {
    int o = it * 4096 + tid * 16;
    gll16((unsigned char*)sT + o, t_in + (size_t)blockIdx.x * 16384 + o);
  }
  #pragma unroll
  for (int it = 0; it < 4; ++it) {
    int o = it * 4096 + tid * 16;
    gll16(sxn + o, (const unsigned char*)xn_sw + (size_t)p0 * 256 + o);
  }
  __syncthreads();
  const int p = tid & 63, dh = tid >> 6;
  {
    float s = 0.f, q = 0.f;
    #pragma unroll
    for (int dd = 0; dd < 32; ++dd) {
      float v = bf2f(sT[(dh * 32 + dd) * 64 + p]);
      s += v; q += v * v;
    }
    ps[dh][p] = s; pq[dh][p] = q;
  }
  __syncthreads();
  if (tid < 64) {
    float s = ps[0][tid] + ps[1][tid] + ps[2][tid] + ps[3][tid];
    float q = pq[0][tid] + pq[1][tid] + pq[2][tid] + pq[3][tid];
    float mean = s * (1.0f / 128.0f);
    float var = q * (1.0f / 128.0f) - mean * mean;
    smean[tid] = mean; srstd[tid] = rsqrtf(var + 1e-5f);
  }
  __syncthreads();
  {
    float mean = smean[p], rstd = srstd[p];
    #pragma unroll
    for (int e = 0; e < 16; ++e) {
      int d0 = dh * 32 + e * 2;
      float v0 = (bf2f(sT[d0 * 64 + p]) - mean) * rstd * now[d0] + nob[d0];
      float v1 = (bf2f(sT[(d0 + 1) * 64 + p]) - mean) * rstd * now[d0 + 1] + nob[d0 + 1];
      unsigned pack = pkbf2(v0, v1);
      *(unsigned*)(sTN + p * 256 + ((d0 * 2) ^ ((p & 7) << 4))) = pack;
    }
  }
  __syncthreads();
  f32x4 accP[2][4] = {}, accG[2][4] = {};
  const unsigned char* wpo = (const unsigned char*)wprep + WP_PO;
  const unsigned char* wgo = (const unsigned char*)wprep + WP_GO;
  #pragma unroll
  for (int ks = 0; ks < 4; ++ks) {
    int kbb = ks * 64 + (lane >> 4) * 16;
    bf16x8 af[2], ag[2], bP[4], bG[4];
    #pragma unroll
    for (int mi = 0; mi < 2; ++mi) {
      int r = wr * 32 + mi * 16 + (lane & 15);
      int off = r * 256 + (kbb ^ ((r & 7) << 4));
      af[mi] = *(const bf16x8*)(sTN + off);
      ag[mi] = *(const bf16x8*)(sxn + off);
    }
    #pragma unroll
    for (int ni = 0; ni < 4; ++ni) {
      int n = wc * 64 + ni * 16 + (lane & 15);
      int off = n * 256 + (kbb ^ ((n & 7) << 4));
      bP[ni] = *(const bf16x8*)(wpo + off);
      bG[ni] = *(const bf16x8*)(wgo + off);
    }
    #pragma unroll
    for (int mi = 0; mi < 2; ++mi)
      #pragma unroll
      for (int ni = 0; ni < 4; ++ni) {
        accP[mi][ni] = __builtin_amdgcn_mfma_f32_16x16x32_bf16(af[mi], bP[ni], accP[mi][ni], 0, 0, 0);
        accG[mi][ni] = __builtin_amdgcn_mfma_f32_16x16x32_bf16(ag[mi], bG[ni], accG[mi][ni], 0, 0, 0);
      }
  }
  // epilogue: stage f32 [64 p][512B], 64B-window XOR by (p>>2)&3 -> dense nt stores
  __syncthreads();
  #pragma unroll
  for (int mi = 0; mi < 2; ++mi)
    #pragma unroll
    for (int ni = 0; ni < 4; ++ni) {
      int nb4 = (wc * 256 + ni * 64 + (lane & 15) * 4);
      int prow = wr * 32 + mi * 16 + (lane >> 4) * 4;
      #pragma unroll
      for (int j = 0; j < 4; ++j) {
        int pp = prow + j;
        float v = accP[mi][ni][j] * sigmoidf_(accG[mi][ni][j]);
        *(float*)(sm + pp * 512 + (nb4 ^ (((pp >> 2) & 3) << 6))) = v;
      }
    }
  __syncthreads();
  #pragma unroll
  for (int it = 0; it < 8; ++it) {
    int idx = it * 256 + tid;
    int pp = idx >> 5, ch = idx & 31;
    uint4 v = *(const uint4*)(sm + pp * 512 + ((ch * 16) ^ (((pp >> 2) & 3) << 6)));
    ntstore16((unsigned char*)out + (size_t)(p0 + pp) * 512 + ch * 16, v);
  }
}

extern "C" void kernel_launch(void* const* d_in, const int* in_sizes, int n_in,
                              void* d_out, int out_size, void* d_ws, size_t ws_size,
                              hipStream_t stream) {
  (void)in_sizes; (void)n_in; (void)out_size; (void)ws_size;
  const float* x         = (const float*)d_in[0];
  const float* mask      = (const float*)d_in[1];
  const float* w_p_in    = (const float*)d_in[2];
  const float* w_g_in    = (const float*)d_in[3];
  const float* w_p_out   = (const float*)d_in[4];
  const float* w_g_out   = (const float*)d_in[5];
  const float* norm_in_w = (const float*)d_in[6];
  const float* norm_in_b = (const float*)d_in[7];
  const float* norm_out_w= (const float*)d_in[8];
  const float* norm_out_b= (const float*)d_in[9];
  float* out = (float*)d_out;

  unsigned char* ws = (unsigned char*)d_ws;
  const size_t SLAB = (size_t)128 * PITCH;          // ~64.5 MiB per d-major buffer
  unsigned char* a_t    = ws;
  unsigned char* b_t    = ws + SLAB;
  unsigned char* t_buf  = ws + 2 * SLAB;
  unsigned short* xn_sw = (unsigned short*)(ws + 3 * SLAB);          // 64 MiB
  unsigned short* wprep = (unsigned short*)(ws + 3 * SLAB + (size_t)NP * 256); // 192 KiB

  kw_prep<<<384, 256, 0, stream>>>(w_p_in, w_g_in, w_g_out, w_p_out, wprep);
  kA_ln<<<4096, 256, 0, stream>>>(x, norm_in_w, norm_in_b, xn_sw);
  kB_gemm<<<8192, 256, 0, stream>>>(xn_sw, mask, wprep, a_t, b_t);
  k2_einsum<<<2048, 512, 0, stream>>>(a_t, b_t, t_buf);
  k3_out<<<4096, 256, 0, stream>>>(t_buf, xn_sw, wprep, norm_out_w, norm_out_b, out);
}